// Round 3
// baseline (789.720 us; speedup 1.0000x reference)
//
#include <hip/hip_runtime.h>
#include <math.h>

typedef float f32x4 __attribute__((ext_vector_type(4)));
typedef __attribute__((ext_vector_type(8))) short bf16x8;

#define DD 256
#define DH 128

// fp32 -> bf16 bits, round-to-nearest-even
__device__ __forceinline__ unsigned short f2bf_rne(float f) {
  unsigned u = __float_as_uint(f);
  unsigned r = (u + 0x7fffu + ((u >> 16) & 1u)) >> 16;
  return (unsigned short)r;
}

// ---------------------------------------------------------------------------
// K0: convert W1 (256x128 fp32 row-major) into MFMA B-fragment order, split
// into bf16 hi + lo. w1hi[((kt*8+nt)*64 + lane)*8 + j] =
//   bf16(W1[kt*32 + (lane>>4)*8 + j][nt*16 + (lane&15)])
// ---------------------------------------------------------------------------
__global__ void ap_prep(const float* __restrict__ W1,
                        unsigned short* __restrict__ w1hi,
                        unsigned short* __restrict__ w1lo) {
  int t = blockIdx.x * blockDim.x + threadIdx.x;  // 0..4095
  if (t >= 64 * 64) return;
  int l = t & 63;
  int tile = t >> 6;  // kt*8 + nt
  int kt = tile >> 3, nt = tile & 7;
  int kbase = kt * 32 + (l >> 4) * 8;
  int col = nt * 16 + (l & 15);
#pragma unroll
  for (int j = 0; j < 8; ++j) {
    float f = W1[(kbase + j) * DH + col];
    unsigned short h = f2bf_rne(f);
    float hf = __uint_as_float((unsigned)h << 16);
    unsigned short lb = f2bf_rne(f - hf);
    w1hi[t * 8 + j] = h;
    w1lo[t * 8 + j] = lb;
  }
}

// ---------------------------------------------------------------------------
// K1: segment boundaries (batch sorted). start[b] = first i with batch[i]>=b
// ---------------------------------------------------------------------------
__global__ void ap_bounds(const int* __restrict__ batch, int* __restrict__ start,
                          int nrows, int bseg) {
  int i = blockIdx.x * blockDim.x + threadIdx.x;
  if (i >= nrows) return;
  int c = batch[i];
  int p = (i == 0) ? -1 : batch[i - 1];
  for (int b = p + 1; b <= c; ++b) start[b] = i;
  if (i == nrows - 1) {
    for (int b = c + 1; b <= bseg; ++b) start[b] = nrows;
  }
}

// ---------------------------------------------------------------------------
// K2: fused per-segment MLP + online-softmax pooling. Block b owns rows
// [start[b], start[b+1]). Per 64-row tile: split-bf16 MFMA MLP -> raw (LDS),
// running segment max m with exp(m_old-m_new) rescale of accumulators,
// P += exp(raw-m)*x (x re-read hits L2), sw += sum(exp(raw-m)).
// Deterministic: one block per segment, fixed-order reductions, no atomics.
// ---------------------------------------------------------------------------
__global__ __launch_bounds__(256)
void ap_fused(const float* __restrict__ x, const unsigned short* __restrict__ w1hi,
              const unsigned short* __restrict__ w1lo, const float* __restrict__ b1,
              const float* __restrict__ W2, const float* __restrict__ b2,
              const int* __restrict__ start, float* __restrict__ P,
              float* __restrict__ mseg, float* __restrict__ sseg, int nrows) {
  __shared__ float ws[64];
  __shared__ f32x4 sredp[4][64];

  const int b = blockIdx.x;
  const int s = start[b], e = start[b + 1];
  const int tid = threadIdx.x;
  const int wv = tid >> 6;
  const int l = tid & 63;
  const int l15 = l & 15, lhi = l >> 4;
  const float bb = *b2;

  float b1f[8], w2f[8];
#pragma unroll
  for (int nt = 0; nt < 8; ++nt) {
    b1f[nt] = b1[nt * 16 + l15];
    w2f[nt] = W2[nt * 16 + l15];
  }

  f32x4 accp = {0.f, 0.f, 0.f, 0.f};  // pooling partial: cols l*4.., rows%4==wv
  float m = -__builtin_inff();
  float sw = 0.f;

  for (int t0 = s; t0 < e; t0 += 64) {
    // ---- MLP for rows t0..t0+63 (wave wv: rows t0+wv*16+..) ----
    long long row = (long long)t0 + wv * 16 + l15;
    long long rowc = row < (long long)nrows ? row : (long long)nrows - 1;
    const float* xr = x + rowc * DD + lhi * 8;

    f32x4 acc[8];
#pragma unroll
    for (int nt = 0; nt < 8; ++nt) acc[nt] = f32x4{0.f, 0.f, 0.f, 0.f};

#pragma unroll
    for (int kt = 0; kt < 8; ++kt) {
      const f32x4 v0 = *(const f32x4*)(xr + kt * 32);
      const f32x4 v1 = *(const f32x4*)(xr + kt * 32 + 4);
      bf16x8 ah, al;
#pragma unroll
      for (int j = 0; j < 8; ++j) {
        float f = (j < 4) ? v0[j] : v1[j - 4];
        unsigned short h = f2bf_rne(f);
        float hf = __uint_as_float((unsigned)h << 16);
        ah[j] = (short)h;
        al[j] = (short)f2bf_rne(f - hf);
      }
      const bf16x8* bh = (const bf16x8*)(w1hi + (size_t)kt * 4096);
      const bf16x8* bl = (const bf16x8*)(w1lo + (size_t)kt * 4096);
#pragma unroll
      for (int nt = 0; nt < 8; ++nt) {
        const bf16x8 Bh = bh[nt * 64 + l];
        const bf16x8 Bl = bl[nt * 64 + l];
        acc[nt] = __builtin_amdgcn_mfma_f32_16x16x32_bf16(ah, Bh, acc[nt], 0, 0, 0);
        acc[nt] = __builtin_amdgcn_mfma_f32_16x16x32_bf16(al, Bh, acc[nt], 0, 0, 0);
        acc[nt] = __builtin_amdgcn_mfma_f32_16x16x32_bf16(ah, Bl, acc[nt], 0, 0, 0);
      }
    }

    // epilogue: relu + b1, dot W2, reduce over 16 col-lanes
    float pr[4];
#pragma unroll
    for (int r = 0; r < 4; ++r) {
      float t = 0.f;
#pragma unroll
      for (int nt = 0; nt < 8; ++nt) t += fmaxf(acc[nt][r] + b1f[nt], 0.f) * w2f[nt];
      pr[r] = t;
    }
#pragma unroll
    for (int mm = 1; mm < 16; mm <<= 1) {
#pragma unroll
      for (int r = 0; r < 4; ++r) pr[r] += __shfl_xor(pr[r], mm, 64);
    }
    // stash raw into LDS; invalid rows (>= e) -> -inf (w=0, excluded from max)
    if (l15 == 0) {
      const long long wrow0 = (long long)t0 + wv * 16 + lhi * 4;
#pragma unroll
      for (int r = 0; r < 4; ++r) {
        ws[wv * 16 + lhi * 4 + r] =
            (wrow0 + r < (long long)e) ? (pr[r] + bb) : -__builtin_inff();
      }
    }
    __syncthreads();

    // ---- online-softmax update (redundant per wave; identical results) ----
    float tv = ws[l];
#pragma unroll
    for (int mm = 1; mm < 64; mm <<= 1) tv = fmaxf(tv, __shfl_xor(tv, mm, 64));
    const float nm = fmaxf(m, tv);          // tile has >=1 valid row -> finite
    const float factor = expf(m - nm);      // m=-inf first tile -> 0 (accp==0)
    m = nm;
    accp *= factor;

    // pooling: wave wv accumulates rows j = q*4+wv, cols l*4..l*4+3
#pragma unroll 4
    for (int q = 0; q < 16; ++q) {
      const int j = q * 4 + wv;
      const float wj = expf(ws[j] - m);     // -inf -> 0
      long long prow = (long long)t0 + j;
      if (prow > (long long)nrows - 1) prow = nrows - 1;
      const f32x4 xv = *(const f32x4*)(x + prow * DD + l * 4);
      accp += wj * xv;
    }

    // sum of w over the tile (fixed-order butterfly; redundant per wave)
    float wl = expf(ws[l] - m);
#pragma unroll
    for (int mm = 1; mm < 64; mm <<= 1) wl += __shfl_xor(wl, mm, 64);
    sw = sw * factor + wl;
    __syncthreads();  // ws consumed; safe to overwrite next tile
  }

  // finalize: combine the 4 wave copies of the pooling accumulator
  sredp[wv][l] = accp;
  __syncthreads();
  if (wv == 0) {
    f32x4 r = ((sredp[0][l] + sredp[1][l]) + sredp[2][l]) + sredp[3][l];
    *(f32x4*)(P + (size_t)b * DD + l * 4) = r;
  }
  if (tid == 0) { mseg[b] = m; sseg[b] = sw; }
}

// ---------------------------------------------------------------------------
// K3: global max M = max_b mseg[b] (single block, deterministic tree)
// ---------------------------------------------------------------------------
__global__ __launch_bounds__(256)
void ap_gmax(const float* __restrict__ mseg, float* __restrict__ Mslot, int bseg) {
  __shared__ float red[256];
  float v = -__builtin_inff();
  for (int i = threadIdx.x; i < bseg; i += 256) v = fmaxf(v, mseg[i]);
  red[threadIdx.x] = v;
  __syncthreads();
  for (int off = 128; off > 0; off >>= 1) {
    if ((int)threadIdx.x < off)
      red[threadIdx.x] = fmaxf(red[threadIdx.x], red[threadIdx.x + off]);
    __syncthreads();
  }
  if (threadIdx.x == 0) *Mslot = red[0];
}

// ---------------------------------------------------------------------------
// K4: out[b][:] = P[b][:] * e_b / ((s_b*e_b/cnt*N + 1e-8) * cnt)
// ---------------------------------------------------------------------------
__global__ __launch_bounds__(64)
void ap_final(const float* __restrict__ P, const float* __restrict__ mseg,
              const float* __restrict__ sseg, const int* __restrict__ start,
              const float* __restrict__ Mslot, float* __restrict__ out, int nrows) {
  const int b = blockIdx.x;
  const int l = threadIdx.x;
  const float M = *Mslot;
  const float eb = expf(mseg[b] - M);
  const int cnt = start[b + 1] - start[b];
  const float cntf = (float)(cnt > 0 ? cnt : 1);
  const float denom = (sseg[b] * eb / cntf) * (float)nrows + 1e-8f;
  const float sc = eb / (denom * cntf);
  f32x4 p = *(const f32x4*)(P + (size_t)b * DD + l * 4);
  p *= sc;
  *(f32x4*)(out + (size_t)b * DD + l * 4) = p;
}

extern "C" void kernel_launch(void* const* d_in, const int* in_sizes, int n_in,
                              void* d_out, int out_size, void* d_ws, size_t ws_size,
                              hipStream_t stream) {
  const float* x     = (const float*)d_in[0];
  const int*   batch = (const int*)d_in[1];
  const float* W1    = (const float*)d_in[2];
  const float* b1    = (const float*)d_in[3];
  const float* W2    = (const float*)d_in[4];
  const float* b2    = (const float*)d_in[5];
  float* out = (float*)d_out;

  const int nrows = in_sizes[1];
  const int bseg = out_size / DD;

  // workspace layout (16B-aligned)
  unsigned short* w1hi = (unsigned short*)d_ws;              // 64 KB
  unsigned short* w1lo = w1hi + 64 * 64 * 8;                 // 64 KB
  float* P    = (float*)(w1lo + 64 * 64 * 8);                // bseg*256 fp32
  float* mseg = P + (size_t)bseg * DD;                       // bseg
  float* sseg = mseg + bseg;                                 // bseg
  float* Mslot = sseg + bseg;                                // 1
  int* start = (int*)(Mslot + 1);                            // bseg+1

  ap_prep<<<16, 256, 0, stream>>>(W1, w1hi, w1lo);
  ap_bounds<<<(nrows + 255) / 256, 256, 0, stream>>>(batch, start, nrows, bseg);
  ap_fused<<<bseg, 256, 0, stream>>>(x, w1hi, w1lo, b1, W2, b2, start, P, mseg,
                                     sseg, nrows);
  ap_gmax<<<1, 256, 0, stream>>>(mseg, Mslot, bseg);
  ap_final<<<bseg, 64, 0, stream>>>(P, mseg, sseg, start, Mslot, out, nrows);
}

// Round 4
// 333.088 us; speedup vs baseline: 2.3709x; 2.3709x over previous
//
#include <hip/hip_runtime.h>
#include <math.h>

typedef float f32x4 __attribute__((ext_vector_type(4)));
typedef __attribute__((ext_vector_type(8))) short bf16x8;

#define DD 256
#define DH 128

// order-preserving float<->uint encoding for deterministic atomicMax
__device__ __forceinline__ unsigned enc_f32(float f) {
  unsigned u = __float_as_uint(f);
  return (u & 0x80000000u) ? ~u : (u | 0x80000000u);
}
__device__ __forceinline__ float dec_f32(unsigned u) {
  return __uint_as_float((u & 0x80000000u) ? (u ^ 0x80000000u) : ~u);
}
// fp32 -> bf16 bits, round-to-nearest-even
__device__ __forceinline__ unsigned short f2bf_rne(float f) {
  unsigned u = __float_as_uint(f);
  unsigned r = (u + 0x7fffu + ((u >> 16) & 1u)) >> 16;
  return (unsigned short)r;
}

// ---------------------------------------------------------------------------
// K0: W1 (256x128 fp32) -> MFMA B-fragment order, split bf16 hi+lo.
// w1hi[((kt*8+nt)*64+lane)*8+j] = bf16(W1[kt*32+(lane>>4)*8+j][nt*16+(lane&15)])
// Also initializes maxslot (runs before ap_mlp on the same stream).
// ---------------------------------------------------------------------------
__global__ void ap_prep(const float* __restrict__ W1,
                        unsigned short* __restrict__ w1hi,
                        unsigned short* __restrict__ w1lo,
                        unsigned* __restrict__ maxslot) {
  int t = blockIdx.x * blockDim.x + threadIdx.x;  // 0..4095
  if (t == 0) *maxslot = 0u;
  if (t >= 64 * 64) return;
  int l = t & 63;
  int tile = t >> 6;  // kt*8 + nt
  int kt = tile >> 3, nt = tile & 7;
  int kbase = kt * 32 + (l >> 4) * 8;
  int col = nt * 16 + (l & 15);
#pragma unroll
  for (int j = 0; j < 8; ++j) {
    float f = W1[(kbase + j) * DH + col];
    unsigned short h = f2bf_rne(f);
    float hf = __uint_as_float((unsigned)h << 16);
    unsigned short lb = f2bf_rne(f - hf);
    w1hi[t * 8 + j] = h;
    w1lo[t * 8 + j] = lb;
  }
}

// ---------------------------------------------------------------------------
// K1: segment boundaries (batch sorted). start[b] = first i with batch[i]>=b
// ---------------------------------------------------------------------------
__global__ void ap_bounds(const int* __restrict__ batch, int* __restrict__ start,
                          int nrows, int bseg) {
  int i = blockIdx.x * blockDim.x + threadIdx.x;
  if (i >= nrows) return;
  int c = batch[i];
  int p = (i == 0) ? -1 : batch[i - 1];
  for (int b = p + 1; b <= c; ++b) start[b] = i;
  if (i == nrows - 1) {
    for (int b = c + 1; b <= bseg; ++b) start[b] = nrows;
  }
}

// ---------------------------------------------------------------------------
// K2: raw[i] = relu(x[i]@W1+b1)@W2+b2 via split-bf16 MFMA (3 products).
// 256 thr = 4 waves; each wave owns 32 rows (two 16-row groups) so every
// B-fragment load (L2-resident, 128 KB) feeds 6 MFMAs -> L2 traffic ~2 GB,
// hidden under the 512 MB HBM x read. Global max via encoded atomicMax.
// ---------------------------------------------------------------------------
__global__ __launch_bounds__(256)
void ap_mlp(const float* __restrict__ x, const unsigned short* __restrict__ w1hi,
            const unsigned short* __restrict__ w1lo, const float* __restrict__ b1,
            const float* __restrict__ W2, const float* __restrict__ b2,
            float* __restrict__ raw, unsigned* __restrict__ maxslot, int nrows) {
  const int tid = threadIdx.x;
  const int wv = tid >> 6;
  const int l = tid & 63;
  const int l15 = l & 15, lhi = l >> 4;

  const long long base = (long long)blockIdx.x * 128 + wv * 32;
  long long r0 = base + l15;
  long long r1 = base + 16 + l15;
  if (r0 > (long long)nrows - 1) r0 = nrows - 1;
  if (r1 > (long long)nrows - 1) r1 = nrows - 1;
  const float* xr0 = x + r0 * DD + lhi * 8;
  const float* xr1 = x + r1 * DD + lhi * 8;

  f32x4 acc0[8], acc1[8];
#pragma unroll
  for (int nt = 0; nt < 8; ++nt) {
    acc0[nt] = f32x4{0.f, 0.f, 0.f, 0.f};
    acc1[nt] = f32x4{0.f, 0.f, 0.f, 0.f};
  }

#pragma unroll
  for (int kt = 0; kt < 8; ++kt) {
    const f32x4 u0 = *(const f32x4*)(xr0 + kt * 32);
    const f32x4 u1 = *(const f32x4*)(xr0 + kt * 32 + 4);
    const f32x4 v0 = *(const f32x4*)(xr1 + kt * 32);
    const f32x4 v1 = *(const f32x4*)(xr1 + kt * 32 + 4);
    bf16x8 ah0, al0, ah1, al1;
#pragma unroll
    for (int j = 0; j < 8; ++j) {
      const float f = (j < 4) ? u0[j] : u1[j - 4];
      const unsigned short h = f2bf_rne(f);
      ah0[j] = (short)h;
      al0[j] = (short)f2bf_rne(f - __uint_as_float((unsigned)h << 16));
      const float g = (j < 4) ? v0[j] : v1[j - 4];
      const unsigned short h2 = f2bf_rne(g);
      ah1[j] = (short)h2;
      al1[j] = (short)f2bf_rne(g - __uint_as_float((unsigned)h2 << 16));
    }
    const bf16x8* bh = (const bf16x8*)(w1hi + (size_t)kt * 4096);
    const bf16x8* bl = (const bf16x8*)(w1lo + (size_t)kt * 4096);
#pragma unroll
    for (int nt = 0; nt < 8; ++nt) {
      const bf16x8 Bh = bh[nt * 64 + l];
      const bf16x8 Bl = bl[nt * 64 + l];
      acc0[nt] = __builtin_amdgcn_mfma_f32_16x16x32_bf16(ah0, Bh, acc0[nt], 0, 0, 0);
      acc0[nt] = __builtin_amdgcn_mfma_f32_16x16x32_bf16(al0, Bh, acc0[nt], 0, 0, 0);
      acc0[nt] = __builtin_amdgcn_mfma_f32_16x16x32_bf16(ah0, Bl, acc0[nt], 0, 0, 0);
      acc1[nt] = __builtin_amdgcn_mfma_f32_16x16x32_bf16(ah1, Bh, acc1[nt], 0, 0, 0);
      acc1[nt] = __builtin_amdgcn_mfma_f32_16x16x32_bf16(al1, Bh, acc1[nt], 0, 0, 0);
      acc1[nt] = __builtin_amdgcn_mfma_f32_16x16x32_bf16(ah1, Bl, acc1[nt], 0, 0, 0);
    }
  }

  // epilogue: relu + b1, dot W2, reduce over the 16 col-lanes per cluster
  float pr0[4], pr1[4];
#pragma unroll
  for (int r = 0; r < 4; ++r) { pr0[r] = 0.f; pr1[r] = 0.f; }
#pragma unroll
  for (int nt = 0; nt < 8; ++nt) {
    const float b1f = b1[nt * 16 + l15];
    const float w2f = W2[nt * 16 + l15];
#pragma unroll
    for (int r = 0; r < 4; ++r) {
      pr0[r] += fmaxf(acc0[nt][r] + b1f, 0.f) * w2f;
      pr1[r] += fmaxf(acc1[nt][r] + b1f, 0.f) * w2f;
    }
  }
#pragma unroll
  for (int mm = 1; mm < 16; mm <<= 1) {
#pragma unroll
    for (int r = 0; r < 4; ++r) {
      pr0[r] += __shfl_xor(pr0[r], mm, 64);
      pr1[r] += __shfl_xor(pr1[r], mm, 64);
    }
  }
  const float bb = *b2;
  const long long w0row = base + lhi * 4;
  const long long w1row = base + 16 + lhi * 4;
  float mymax = -3.4e38f;
#pragma unroll
  for (int r = 0; r < 4; ++r) {
    const float s0 = pr0[r] + bb;
    const float s1 = pr1[r] + bb;
    if (w0row + r < (long long)nrows) {
      if (l15 == 0) raw[w0row + r] = s0;
      mymax = fmaxf(mymax, s0);
    }
    if (w1row + r < (long long)nrows) {
      if (l15 == 0) raw[w1row + r] = s1;
      mymax = fmaxf(mymax, s1);
    }
  }
  mymax = fmaxf(mymax, __shfl_xor(mymax, 16, 64));
  mymax = fmaxf(mymax, __shfl_xor(mymax, 32, 64));
  __shared__ float wmax[4];
  if (l == 0) wmax[wv] = mymax;
  __syncthreads();
  if (tid == 0) {
    atomicMax(maxslot,
              enc_f32(fmaxf(fmaxf(wmax[0], wmax[1]), fmaxf(wmax[2], wmax[3]))));
  }
}

// ---------------------------------------------------------------------------
// K3: block per segment. Pass A: sum_w = sum exp(raw-M) (fixed-order tree).
// Pass B: out[b] = (sum exp(raw-M)*x) / ((sum_w/cnt*N + 1e-8)*cnt).
// raw segment (~2 KB) is cache-hot for the second pass. Deterministic.
// ---------------------------------------------------------------------------
__global__ __launch_bounds__(256)
void ap_pool(const float* __restrict__ x, const float* __restrict__ raw,
             const int* __restrict__ start, const unsigned* __restrict__ maxslot,
             float* __restrict__ out, int nrows) {
  __shared__ float sred[256];
  __shared__ f32x4 credp[4][64];
  const int b = blockIdx.x;
  const int s = start[b], e = start[b + 1];
  const int tid = threadIdx.x;
  const float M = dec_f32(*maxslot);

  // pass A: segment sum of w
  float a = 0.f;
  for (int i = s + tid; i < e; i += 256) a += expf(raw[i] - M);
  sred[tid] = a;
  __syncthreads();
  for (int off = 128; off > 0; off >>= 1) {
    if (tid < off) sred[tid] += sred[tid + off];
    __syncthreads();
  }
  const float sum = sred[0];
  const int cnt = e - s;
  const float cntf = (float)(cnt > 0 ? cnt : 1);
  const float scale = 1.0f / (((sum / cntf) * (float)nrows + 1e-8f) * cntf);

  // pass B: weighted sum of rows; wave rg handles rows == rg (mod 4)
  const int dq = tid & 63;
  const int rg = tid >> 6;
  f32x4 acc = {0.f, 0.f, 0.f, 0.f};
  int i = s + rg;
  for (; i + 4 < e; i += 8) {
    const float wa = expf(raw[i] - M);
    const float wb = expf(raw[i + 4] - M);
    const f32x4 xa = *(const f32x4*)(x + (long long)i * DD + dq * 4);
    const f32x4 xb = *(const f32x4*)(x + (long long)(i + 4) * DD + dq * 4);
    acc += wa * xa + wb * xb;
  }
  if (i < e) {
    const float wa = expf(raw[i] - M);
    const f32x4 xa = *(const f32x4*)(x + (long long)i * DD + dq * 4);
    acc += wa * xa;
  }
  credp[rg][dq] = acc;
  __syncthreads();
  if (rg == 0) {
    f32x4 r = ((credp[0][dq] + credp[1][dq]) + credp[2][dq]) + credp[3][dq];
    r *= scale;
    *(f32x4*)(out + (long long)b * DD + dq * 4) = r;
  }
}

extern "C" void kernel_launch(void* const* d_in, const int* in_sizes, int n_in,
                              void* d_out, int out_size, void* d_ws, size_t ws_size,
                              hipStream_t stream) {
  const float* x     = (const float*)d_in[0];
  const int*   batch = (const int*)d_in[1];
  const float* W1    = (const float*)d_in[2];
  const float* b1    = (const float*)d_in[3];
  const float* W2    = (const float*)d_in[4];
  const float* b2    = (const float*)d_in[5];
  float* out = (float*)d_out;

  const int nrows = in_sizes[1];
  const int bseg = out_size / DD;

  // workspace layout (16B-aligned)
  unsigned short* w1hi = (unsigned short*)d_ws;              // 64 KB
  unsigned short* w1lo = w1hi + 64 * 64 * 8;                 // 64 KB
  float* raw = (float*)(w1lo + 64 * 64 * 8);                 // nrows fp32
  int* start = (int*)(raw + nrows);                          // bseg+1
  unsigned* maxslot = (unsigned*)(start + bseg + 1);         // 1

  ap_prep<<<16, 256, 0, stream>>>(W1, w1hi, w1lo, maxslot);
  ap_bounds<<<(nrows + 255) / 256, 256, 0, stream>>>(batch, start, nrows, bseg);
  ap_mlp<<<(nrows + 127) / 128, 256, 0, stream>>>(x, w1hi, w1lo, b1, W2, b2, raw,
                                                  maxslot, nrows);
  ap_pool<<<bseg, 256, 0, stream>>>(x, raw, start, maxslot, out, nrows);
}